// Round 3
// baseline (3092.544 us; speedup 1.0000x reference)
//
#include <hip/hip_runtime.h>

// LSTM scan, fused x@W_ih.T + h@W_hh.T, bf16 MFMA 16x16x32.
// 256 WGs = 8 batch-groups(32 batches) x 32 members(16 hidden units / 64 gate rows).
// W B-fragments register/AGPR-resident per wave (step-invariant).
// R4: speculative early h-load + parity validate + cheap flag retry.
//  - bulk h(t-1) loads + wave-flag poll issued BEFORE the x-MFMA phase;
//    parity (bit14 of bf16, |h|<1) validated AFTER -> zero exposed LLC RT
//    in the common case. Early issue is safe: peers cannot be >1 step ahead
//    (they would need our flag), so no mid-read overwrite; staleness is
//    caught by parity and retried.
//  - retry path: spin on per-wave flags (8B/lane) then ONE bulk reload
//    (flags >= t guarantee freshness). Kills the 16KB-per-retry storm.
//  - v_cvt_pk_bf16_f32 for f32->bf16x2 pack (5x fewer VALU than bit-ops).
//  - 4 accumulator chains (even/odd kk) halve exposed MFMA latency.
//  - rule #18: s_waitcnt vmcnt(0) asm + sched_barrier(0) before any read
//    of early-issued load registers.

#define T_STEPS 256
#define BATCH   256
#define INP     512
#define HID     512
#define GROUPS  8
#define MEMB    32
#define BT      32          // batches per group
#define NWG     (GROUPS*MEMB)
#define NTHR    256
#define XBUF    65536       // one x step-slice: 32 rows x 512 f32
#define K8OFF   (2*XBUF)
#define LDS_BYTES (2*XBUF + T_STEPS*BT)   // 139264
#define PARM    0x40004000u               // bf16 bit14 pair mask

typedef float  f32x4  __attribute__((ext_vector_type(4)));
typedef short  bf16x8 __attribute__((ext_vector_type(8)));
typedef unsigned int u32x4 __attribute__((ext_vector_type(4)));
typedef unsigned int u32x2 __attribute__((ext_vector_type(2)));

struct HF { u32x4 h[16]; };

typedef const __attribute__((address_space(1))) void gas_v;
typedef __attribute__((address_space(3))) void las_v;
__device__ __forceinline__ void gld_lds16(const void* g, void* l) {
  __builtin_amdgcn_global_load_lds((gas_v*)g, (las_v*)l, 16, 0, 0);
}

__device__ __forceinline__ unsigned short f2bf(float f) {
  unsigned u = __builtin_bit_cast(unsigned, f);
  return (unsigned short)((u + 0x8000u) >> 16);
}
// packed RNE f32->bf16 conversion: 4 instrs per 8 elements
__device__ __forceinline__ bf16x8 cvt8pk(float4 a, float4 b) {
  union { unsigned u[4]; bf16x8 v; } r;
  asm("v_cvt_pk_bf16_f32 %0, %1, %2" : "=v"(r.u[0]) : "v"(a.x), "v"(a.y));
  asm("v_cvt_pk_bf16_f32 %0, %1, %2" : "=v"(r.u[1]) : "v"(a.z), "v"(a.w));
  asm("v_cvt_pk_bf16_f32 %0, %1, %2" : "=v"(r.u[2]) : "v"(b.x), "v"(b.y));
  asm("v_cvt_pk_bf16_f32 %0, %1, %2" : "=v"(r.u[3]) : "v"(b.z), "v"(b.w));
  return r.v;
}
__device__ __forceinline__ float sigf(float x) {
  return __fdividef(1.0f, 1.0f + __expf(-x));
}
__device__ __forceinline__ float tanh_(float x) {
  float e = __expf(-2.0f * fabsf(x));
  float t = __fdividef(1.0f - e, 1.0f + e);
  return copysignf(t, x);
}
__device__ __forceinline__ f32x4 shflx4(f32x4 v, int m) {
  f32x4 r;
  r[0]=__shfl_xor(v[0],m,64); r[1]=__shfl_xor(v[1],m,64);
  r[2]=__shfl_xor(v[2],m,64); r[3]=__shfl_xor(v[3],m,64);
  return r;
}

// issue 16 x 16B LLC-coherent loads (one batch-row fragment set), NO wait.
__device__ __forceinline__ void llc_issue_h(HF& o, const void* p) {
  unsigned long long a = (unsigned long long)p;
  asm volatile(
    "global_load_dwordx4 %[h0],  %[a], off sc0 sc1\n\t"
    "global_load_dwordx4 %[h1],  %[a], off offset:64 sc0 sc1\n\t"
    "global_load_dwordx4 %[h2],  %[a], off offset:128 sc0 sc1\n\t"
    "global_load_dwordx4 %[h3],  %[a], off offset:192 sc0 sc1\n\t"
    "global_load_dwordx4 %[h4],  %[a], off offset:256 sc0 sc1\n\t"
    "global_load_dwordx4 %[h5],  %[a], off offset:320 sc0 sc1\n\t"
    "global_load_dwordx4 %[h6],  %[a], off offset:384 sc0 sc1\n\t"
    "global_load_dwordx4 %[h7],  %[a], off offset:448 sc0 sc1\n\t"
    "global_load_dwordx4 %[h8],  %[a], off offset:512 sc0 sc1\n\t"
    "global_load_dwordx4 %[h9],  %[a], off offset:576 sc0 sc1\n\t"
    "global_load_dwordx4 %[h10], %[a], off offset:640 sc0 sc1\n\t"
    "global_load_dwordx4 %[h11], %[a], off offset:704 sc0 sc1\n\t"
    "global_load_dwordx4 %[h12], %[a], off offset:768 sc0 sc1\n\t"
    "global_load_dwordx4 %[h13], %[a], off offset:832 sc0 sc1\n\t"
    "global_load_dwordx4 %[h14], %[a], off offset:896 sc0 sc1\n\t"
    "global_load_dwordx4 %[h15], %[a], off offset:960 sc0 sc1"
    : [h0]"=v"(o.h[0]),  [h1]"=v"(o.h[1]),  [h2]"=v"(o.h[2]),  [h3]"=v"(o.h[3]),
      [h4]"=v"(o.h[4]),  [h5]"=v"(o.h[5]),  [h6]"=v"(o.h[6]),  [h7]"=v"(o.h[7]),
      [h8]"=v"(o.h[8]),  [h9]"=v"(o.h[9]),  [h10]"=v"(o.h[10]),[h11]"=v"(o.h[11]),
      [h12]"=v"(o.h[12]),[h13]"=v"(o.h[13]),[h14]"=v"(o.h[14]),[h15]"=v"(o.h[15])
    : [a]"v"(a)
    : "memory");
}
__device__ __forceinline__ u32x2 flag_issue(const void* p) {
  u32x2 f; unsigned long long a = (unsigned long long)p;
  asm volatile("global_load_dwordx2 %0, %1, off sc0 sc1"
               : "=v"(f) : "v"(a) : "memory");
  return f;
}
// drain all VMEM; fence the scheduler so register reads can't hoist above
__device__ __forceinline__ void vmwait0() {
  asm volatile("s_waitcnt vmcnt(0)" ::: "memory");
  __builtin_amdgcn_sched_barrier(0);
}

__global__ void __launch_bounds__(NTHR, 1)
lstm_fused(const float* __restrict__ x, const int* __restrict__ dones,
           const float* __restrict__ Wih, const float* __restrict__ Whh,
           const float* __restrict__ bih, const float* __restrict__ bhh,
           float* __restrict__ out, unsigned* __restrict__ hb32,
           unsigned long long* __restrict__ hb64, int* __restrict__ flags)
{
  extern __shared__ char smem_raw[];
  unsigned short* wst   = (unsigned short*)smem_raw;        // init only
  char*           xring = smem_raw;                         // loop: 2 x 64KB
  unsigned char*  k8    = (unsigned char*)smem_raw + K8OFF; // keeps[T][BT]

  const int tid  = threadIdx.x;
  const int lane = tid & 63;
  const int wv   = tid >> 6;
  const int grp  = blockIdx.x >> 5;
  const int memb = blockIdx.x & 31;
  const int b0   = grp * BT;
  const int j0   = memb * 16;
  const int mtile = wv & 1;        // which 16-batch M tile
  const int hh    = wv >> 1;       // which hidden octet of the member's 16
  const int q    = lane >> 4;
  const int n    = lane & 15;
  const int r    = n & 7;

  // ---- one-time: W slice (64 gate rows x concat-K 1024) -> LDS, B-frag order
  for (int e = tid; e < 64*1024; e += NTHR) {
    int s = e >> 10, k = e & 1023;
    int nf = s >> 4, nn = s & 15;
    int gp = nf & 1;
    int hloc = (nf >> 1)*8 + (nn & 7);
    int gate = (nn < 8) ? (gp ? 2 : 0) : (gp ? 3 : 1);
    int grow = gate*HID + j0 + hloc;
    float v = (k < INP) ? Wih[grow*INP + k] : Whh[grow*HID + (k - INP)];
    int kk = k >> 5, qq = (k >> 3) & 3, j = k & 7;
    wst[((kk*4 + nf)*64 + qq*16 + nn)*8 + j] = f2bf(v);
  }
  // ---- one-time: all keeps -> LDS (u8)
  for (int idx = tid; idx < T_STEPS*BT; idx += NTHR) {
    int tt = idx >> 5, bb = idx & 31;
    k8[idx] = (unsigned char)(1 - dones[tt*BATCH + b0 + bb]);
  }
  __syncthreads();

  // ---- B fragments into registers/AGPRs (step-invariant).
  const int nf0 = 2*hh;
  bf16x8 B0[32], B1[32];
  #pragma unroll
  for (int kk = 0; kk < 32; ++kk) {
    B0[kk] = *(const bf16x8*)(wst + ((kk*4 + nf0    )*64 + lane)*8);
    B1[kk] = *(const bf16x8*)(wst + ((kk*4 + nf0 + 1)*64 + lane)*8);
  }
  __syncthreads();   // W-staging LDS now dead; xring may overwrite it

  const int jmy = j0 + hh*8 + r;   // this lane's hidden unit
  const float bi  = bih[0*HID + jmy] + bhh[0*HID + jmy];
  const float bf_ = bih[1*HID + jmy] + bhh[1*HID + jmy];
  const float bg  = bih[2*HID + jmy] + bhh[2*HID + jmy];
  const float bo  = bih[3*HID + jmy] + bhh[3*HID + jmy];

  float h_s[2] = {0.f, 0.f}, c_s[2] = {0.f, 0.f};
  const bool lo  = (n < 8);
  const int  rgb = lo ? 0 : 2;
  float* hidb = out + (size_t)T_STEPS*BATCH*HID;
  const int bbA = b0 + mtile*16 + n;        // A-row batch for MFMA loads

  // per-wave flag slot; poll covers all 128 wave-flags of the group
  int* myflag = flags + blockIdx.x*4 + wv;
  const int* fp2 = flags + grp*128 + 2*lane;

  // ---- per-wave DMA of the wave's OWN mtile half (32KB) into the LDS ring.
  auto stage_x = [&](int ts) {
    char* base = xring + (ts & 1)*XBUF + mtile*32768;
    const int lp   = lane ^ ((lane >> 3) & 1);
    const int row  = mtile*16 + ((lp >> 1) & 15);
    const int coff = ((lp >> 5) << 3) + (lp & 1)*4;
    const float* src0 = x + (size_t)(ts*BATCH + b0 + row)*INP + coff;
    #pragma unroll
    for (int e = 0; e < 32; ++e)
      gld_lds16(src0 + e*16, base + e*1024);
  };

  // ---- prologue: x(0) into buf 0 (own half; own vmcnt guards own reads)
  stage_x(0);
  vmwait0();

  const char* xbase = xring + mtile*32768 + lane*32;
  const int   sx    = ((lane >> 2) & 1) << 4;   // read-side swizzle bit
  const f32x4 zf4 = {0.f,0.f,0.f,0.f};

  for (int t = 0; t < T_STEPS; ++t) {
    // ---- 1. early issues: flag poll + speculative bulk h(t-1) load
    const void* hbp = (const char*)(hb64 + ((t+1)&1)*(BATCH*HID/4)
                                  + (size_t)bbA*(HID/4)) + q*16;
    u32x2 flv = flag_issue(fp2);
    HF hf;
    llc_issue_h(hf, hbp);
    // ---- 2. DMA of x(t+1): drained by this step's vmwait0 below
    if (t + 1 < T_STEPS) stage_x(t + 1);

    // ---- 3. x part from swizzled LDS ring (slot t&1); 4 acc chains
    f32x4 a0e = zf4, a0o = zf4, a1e = zf4, a1o = zf4;
    const char* xb = xbase + (t & 1)*XBUF;
    #pragma unroll
    for (int kk = 0; kk < 16; kk += 2) {
      float4 xa = *(const float4*)(xb + kk*2048 + sx);
      float4 xc = *(const float4*)(xb + kk*2048 + (16 ^ sx));
      bf16x8 ae = cvt8pk(xa, xc);
      a0e = __builtin_amdgcn_mfma_f32_16x16x32_bf16(ae, B0[kk], a0e, 0, 0, 0);
      a1e = __builtin_amdgcn_mfma_f32_16x16x32_bf16(ae, B1[kk], a1e, 0, 0, 0);
      float4 xd = *(const float4*)(xb + (kk+1)*2048 + sx);
      float4 xe = *(const float4*)(xb + (kk+1)*2048 + (16 ^ sx));
      bf16x8 ao = cvt8pk(xd, xe);
      a0o = __builtin_amdgcn_mfma_f32_16x16x32_bf16(ao, B0[kk+1], a0o, 0, 0, 0);
      a1o = __builtin_amdgcn_mfma_f32_16x16x32_bf16(ao, B1[kk+1], a1o, 0, 0, 0);
    }

    // ---- 4. drain early loads (+DMA), then validate parity
    vmwait0();
    const int ebit = (t == 0) ? 1 : (((t - 1) >> 1) & 1);
    bool fresh;
    if (ebit) {
      unsigned acc = 0xFFFFFFFFu;
      #pragma unroll
      for (int kk = 0; kk < 16; ++kk) {
        u32x4 v = hf.h[kk];
        acc &= v[0] & v[1] & v[2] & v[3];
      }
      fresh = __all((acc & PARM) == PARM);
    } else {
      unsigned acc = 0u;
      #pragma unroll
      for (int kk = 0; kk < 16; ++kk) {
        u32x4 v = hf.h[kk];
        acc |= v[0] | v[1] | v[2] | v[3];
      }
      fresh = __all((acc & PARM) == 0u);
    }
    if (!fresh) {
      // cheap retry: spin on 8B wave-flags, then ONE guaranteed-fresh reload
      u32x2 f = flv;
      while (!__all(((int)f[0] >= t) && ((int)f[1] >= t))) {
        __builtin_amdgcn_s_sleep(1);
        f = flag_issue(fp2);
        vmwait0();
      }
      llc_issue_h(hf, hbp);
      vmwait0();
    }

    // ---- 5. h MFMAs (strip parity bit; zero rows where done)
    const unsigned char kA = k8[t*BT + mtile*16 + n];
    const unsigned msk = kA ? (ebit ? ~PARM : 0xFFFFFFFFu) : 0u;
    #pragma unroll
    for (int kk = 0; kk < 16; kk += 2) {
      u32x4 v = hf.h[kk];
      v[0] &= msk; v[1] &= msk; v[2] &= msk; v[3] &= msk;
      bf16x8 ae = __builtin_bit_cast(bf16x8, v);
      a0e = __builtin_amdgcn_mfma_f32_16x16x32_bf16(ae, B0[16+kk], a0e, 0, 0, 0);
      a1e = __builtin_amdgcn_mfma_f32_16x16x32_bf16(ae, B1[16+kk], a1e, 0, 0, 0);
      u32x4 w = hf.h[kk+1];
      w[0] &= msk; w[1] &= msk; w[2] &= msk; w[3] &= msk;
      bf16x8 ao = __builtin_bit_cast(bf16x8, w);
      a0o = __builtin_amdgcn_mfma_f32_16x16x32_bf16(ao, B0[17+kk], a0o, 0, 0, 0);
      a1o = __builtin_amdgcn_mfma_f32_16x16x32_bf16(ao, B1[17+kk], a1o, 0, 0, 0);
    }
    f32x4 acc0 = a0e + a0o, acc1 = a1e + a1o;

    // ---- gates: lanes n and n^8 swap halves (i,f in acc0; g,o in acc1) ----
    f32x4 oa = shflx4(acc0, 8), ob = shflx4(acc1, 8);
    f32x4 I = lo ? acc0 : oa;
    f32x4 F = lo ? oa : acc0;
    f32x4 G = lo ? acc1 : ob;
    f32x4 O = lo ? ob : acc1;

    float hnv[2], hrv[2], crv[2];
    #pragma unroll
    for (int u = 0; u < 2; ++u) {
      int rg = rgb + u;
      int lb = mtile*16 + q*4 + rg;
      float kp = (float)k8[t*BT + lb];
      float hr = h_s[u]*kp, cr = c_s[u]*kp;
      float iv  = sigf (I[rg] + bi);
      float fv_ = sigf (F[rg] + bf_);
      float gv  = tanh_(G[rg] + bg);
      float ov  = sigf (O[rg] + bo);
      float cn = fv_*cr + iv*gv;
      float hn = ov*tanh_(cn);
      h_s[u] = hn; c_s[u] = cn;
      hnv[u] = hn; hrv[u] = hr; crv[u] = cr;
    }

    // ---- h(t) -> LLC first (peer-visible ASAP), parity bit embedded
    {
      float send  = (n & 1) ? hnv[0] : hnv[1];
      float other = __shfl_xor(send, 1, 64);
      int lb0 = mtile*16 + q*4 + rgb;
      int lbm = (n & 1) ? lb0 + 1 : lb0;
      float vlo = (n & 1) ? other  : hnv[0];
      float vhi = (n & 1) ? hnv[1] : other;
      unsigned dw;
      asm("v_cvt_pk_bf16_f32 %0, %1, %2" : "=v"(dw) : "v"(vlo), "v"(vhi));
      if ((t >> 1) & 1) dw |= PARM;
      unsigned* dst = hb32 + (t&1)*(BATCH*HID/2)
                    + (size_t)(b0 + lbm)*(HID/2) + (jmy >> 1);
      __hip_atomic_store(dst, dw, __ATOMIC_RELAXED, __HIP_MEMORY_SCOPE_AGENT);
    }

    // ---- drain h-store (+DMA), post per-wave flag, then bulk HBM stores
    vmwait0();
    __hip_atomic_store(myflag, t + 1,
                       __ATOMIC_RELAXED, __HIP_MEMORY_SCOPE_AGENT);
    #pragma unroll
    for (int u = 0; u < 2; ++u) {
      int lb = mtile*16 + q*4 + rgb + u;
      int bb = b0 + lb;
      out [(size_t)(t*BATCH + bb)*HID + jmy]       = hnv[u];
      hidb[((size_t)(t*2+0)*BATCH + bb)*HID + jmy] = hrv[u];
      hidb[((size_t)(t*2+1)*BATCH + bb)*HID + jmy] = crv[u];
    }
  }
}

extern "C" void kernel_launch(void* const* d_in, const int* in_sizes, int n_in,
                              void* d_out, int out_size, void* d_ws, size_t ws_size,
                              hipStream_t stream) {
  (void)in_sizes; (void)n_in; (void)out_size; (void)ws_size;
  const float* x   = (const float*)d_in[0];
  const int*   dn  = (const int*)  d_in[1];
  const float* Wih = (const float*)d_in[2];
  const float* Whh = (const float*)d_in[3];
  const float* bih = (const float*)d_in[4];
  const float* bhh = (const float*)d_in[5];
  float* out = (float*)d_out;

  unsigned*           hb32 = (unsigned*)d_ws;
  unsigned long long* hb64 = (unsigned long long*)d_ws;
  size_t hbuf_bytes = (size_t)2*BATCH*HID*sizeof(unsigned short);   // 512 KB
  int* flags = (int*)((char*)d_ws + hbuf_bytes);                    // 1024 ints

  // hb: 0x40 pattern = parity bit14 set everywhere; masked value ~3e-39 ~= 0.
  hipMemsetAsync(d_ws, 0x40, hbuf_bytes, stream);
  hipMemsetAsync(flags, 0, NWG*4*sizeof(int), stream);
  hipFuncSetAttribute((const void*)lstm_fused,
                      hipFuncAttributeMaxDynamicSharedMemorySize, LDS_BYTES);
  lstm_fused<<<dim3(NWG), dim3(NTHR), LDS_BYTES, stream>>>(
      x, dn, Wih, Whh, bih, bhh, out, hb32, hb64, flags);
}